// Round 1
// baseline (1708.221 us; speedup 1.0000x reference)
//
#include <hip/hip_runtime.h>
#include <hip/hip_bf16.h>

// FLGNN baseline (fp32, no MFMA yet). Structure:
//   CSR build (once/call) -> input GEMM -> 3x [memberships, rule-mix GEMM,
//   CSR aggregate, BN stats, BN apply+residual] -> head softmax.
// Workspace use: ~58 MB (3 NxH f32 buffers + w + CSR arrays).

#define NN 32768
#define NE 1048576
#define H 128
#define R 16
#define NL 3
#define ODIM 40

// ---------------- CSR build ----------------
__global__ void k_hist(const int* __restrict__ dst, int* __restrict__ counts) {
    int e = blockIdx.x * blockDim.x + threadIdx.x;
    if (e < NE) atomicAdd(&counts[dst[e]], 1);
}

__global__ __launch_bounds__(1024) void k_scan(const int* __restrict__ counts,
                                               int* __restrict__ row_start,
                                               int* __restrict__ cursor,
                                               float* __restrict__ invdeg) {
    __shared__ int ssum[1024];
    int t = threadIdx.x;
    int base = t * 32;
    int s = 0;
    for (int i = 0; i < 32; i++) s += counts[base + i];
    ssum[t] = s;
    __syncthreads();
    for (int off = 1; off < 1024; off <<= 1) {
        int v = (t >= off) ? ssum[t - off] : 0;
        __syncthreads();
        ssum[t] += v;
        __syncthreads();
    }
    int run = (t == 0) ? 0 : ssum[t - 1];
    for (int i = 0; i < 32; i++) {
        int c = counts[base + i];
        row_start[base + i] = run;
        cursor[base + i] = run;
        invdeg[base + i] = 1.0f / fmaxf((float)c, 1.0f);
        run += c;
    }
    if (t == 1023) row_start[NN] = run;
}

__global__ void k_fill(const int* __restrict__ src, const int* __restrict__ dst,
                       int* __restrict__ cursor, int* __restrict__ esrc) {
    int e = blockIdx.x * blockDim.x + threadIdx.x;
    if (e < NE) {
        int p = atomicAdd(&cursor[dst[e]], 1);
        esrc[p] = src[e];
    }
}

// ---------------- input layer: h = relu(x @ W_in + b_in) ----------------
__global__ __launch_bounds__(128) void k_in(const float* __restrict__ x,
                                            const float* __restrict__ W,
                                            const float* __restrict__ b,
                                            float* __restrict__ h) {
    __shared__ float xs[H];
    int n = blockIdx.x, t = threadIdx.x;
    xs[t] = x[n * H + t];
    __syncthreads();
    float acc = b[t];
#pragma unroll 8
    for (int k = 0; k < H; k++) acc = fmaf(xs[k], W[k * H + t], acc);
    h[n * H + t] = fmaxf(acc, 0.0f);
}

// ---------------- memberships: w[n,r] = softmax_r(-mean_j d2) ----------------
__global__ __launch_bounds__(128) void k_memb(const float* __restrict__ h,
                                              const float* __restrict__ centers,
                                              const float* __restrict__ widths,
                                              float* __restrict__ wout) {
    __shared__ float hs[H];
    __shared__ float sm[R];
    int n = blockIdx.x, t = threadIdx.x;
    hs[t] = h[n * H + t];
    __syncthreads();
    int r = t >> 3, lane = t & 7;
    float s = 0.0f;
#pragma unroll
    for (int j = lane; j < H; j += 8) {
        float c = centers[r * H + j];
        float wd = widths[r * H + j];
        float d = hs[j] - c;
        s += d * d * (0.5f / (wd * wd));
    }
    s += __shfl_down(s, 4, 8);
    s += __shfl_down(s, 2, 8);
    s += __shfl_down(s, 1, 8);
    if (lane == 0) sm[r] = s * (1.0f / 128.0f);
    __syncthreads();
    if (t < R) {
        float v = -sm[t];
        float m = v;
        for (int off = 8; off; off >>= 1) m = fmaxf(m, __shfl_xor(m, off, R));
        float e = __expf(v - m);
        float sum = e;
        for (int off = 8; off; off >>= 1) sum += __shfl_xor(sum, off, R);
        wout[n * R + t] = e / sum;
    }
}

// ---------------- rule-mix GEMM: msg = (w (x) h) @ Wc_l + w @ bc_l ----------
// C[N,128] = A'[N,2048] x B[2048,128], A'[n, r*128+j] = w[n,r]*h[n,j]
// Tile: BM=64 rows, BN=128 cols (full), BK=32. 256 thr, micro 4 rows x 8 cols.
__global__ __launch_bounds__(256) void k_gemm(const float* __restrict__ h,
                                              const float* __restrict__ wgt,
                                              const float* __restrict__ B,
                                              const float* __restrict__ bc,
                                              float* __restrict__ msg) {
    __shared__ float As[64][33];   // [m][kk], +1 pad
    __shared__ float Bs[32][128];  // [kk][col]
    int tid = threadIdx.x;
    int row0 = blockIdx.x * 64;
    int col0 = (tid & 15) * 8;
    int m0 = (tid >> 4) * 4;
    int akk = tid & 31, am0 = tid >> 5;

    float acc[4][8];
#pragma unroll
    for (int i = 0; i < 4; i++)
#pragma unroll
        for (int j = 0; j < 8; j++) acc[i][j] = 0.0f;

    for (int k0 = 0; k0 < R * H; k0 += 32) {
        int r = k0 >> 7, j0 = k0 & 127;
        // stage A' tile: As[m][kk] = h[row0+m, j0+kk] * w[row0+m, r]
#pragma unroll
        for (int i = 0; i < 8; i++) {
            int m = am0 + i * 8;
            int row = row0 + m;
            As[m][akk] = h[row * H + j0 + akk] * wgt[row * R + r];
        }
        // stage B tile (coalesced float4)
        const float4* Bg = (const float4*)(B + k0 * H);
#pragma unroll
        for (int i = 0; i < 4; i++) {
            int i4 = tid + i * 256;
            int kk = i4 >> 5, c4 = i4 & 31;
            ((float4*)&Bs[kk][0])[c4] = Bg[kk * 32 + c4];
        }
        __syncthreads();
#pragma unroll
        for (int kk = 0; kk < 32; kk++) {
            float4 b0 = *(const float4*)&Bs[kk][col0];
            float4 b1 = *(const float4*)&Bs[kk][col0 + 4];
            float bv[8] = {b0.x, b0.y, b0.z, b0.w, b1.x, b1.y, b1.z, b1.w};
#pragma unroll
            for (int i = 0; i < 4; i++) {
                float a = As[m0 + i][kk];
#pragma unroll
                for (int j = 0; j < 8; j++) acc[i][j] = fmaf(a, bv[j], acc[i][j]);
            }
        }
        __syncthreads();
    }
    // epilogue: firing-weighted bias + store
#pragma unroll
    for (int i = 0; i < 4; i++) {
        int row = row0 + m0 + i;
        float bias[8] = {0, 0, 0, 0, 0, 0, 0, 0};
#pragma unroll
        for (int r = 0; r < R; r++) {
            float wr = wgt[row * R + r];
            const float* bcr = bc + r * H + col0;
#pragma unroll
            for (int j = 0; j < 8; j++) bias[j] = fmaf(wr, bcr[j], bias[j]);
        }
        float4 o0 = {acc[i][0] + bias[0], acc[i][1] + bias[1],
                     acc[i][2] + bias[2], acc[i][3] + bias[3]};
        float4 o1 = {acc[i][4] + bias[4], acc[i][5] + bias[5],
                     acc[i][6] + bias[6], acc[i][7] + bias[7]};
        *(float4*)&msg[row * H + col0] = o0;
        *(float4*)&msg[row * H + col0 + 4] = o1;
    }
}

// ---------------- CSR aggregate: a = relu(mean over in-edges of msg[src]) ----
__global__ __launch_bounds__(128) void k_agg(const float* __restrict__ msg,
                                             const int* __restrict__ row_start,
                                             const int* __restrict__ esrc,
                                             const float* __restrict__ invdeg,
                                             float* __restrict__ a) {
    int n = blockIdx.x, t = threadIdx.x;
    int b = row_start[n], e = row_start[n + 1];
    float acc = 0.0f;
    for (int i = b; i < e; i++) {
        int s = esrc[i];
        acc += msg[s * H + t];
    }
    a[n * H + t] = fmaxf(acc * invdeg[n], 0.0f);
}

// ---------------- BatchNorm stats (sum, sumsq per channel) ----------------
__global__ __launch_bounds__(128) void k_bnstats(const float* __restrict__ a,
                                                 float* __restrict__ sums) {
    int t = threadIdx.x;
    float s = 0.0f, s2 = 0.0f;
    for (int n = blockIdx.x; n < NN; n += gridDim.x) {
        float v = a[n * H + t];
        s += v;
        s2 += v * v;
    }
    atomicAdd(&sums[t], s);
    atomicAdd(&sums[H + t], s2);
}

// ---------------- BN apply + residual: h += gamma*(a-mu)*rsqrt(var)+beta ----
__global__ __launch_bounds__(256) void k_bnapply(const float* __restrict__ a,
                                                 const float* __restrict__ sums,
                                                 const float* __restrict__ gamma,
                                                 const float* __restrict__ beta,
                                                 float* __restrict__ h) {
    int idx = blockIdx.x * 256 + threadIdx.x;
    int c = idx & (H - 1);
    float mu = sums[c] * (1.0f / NN);
    float var = sums[H + c] * (1.0f / NN) - mu * mu;
    float inv = rsqrtf(var + 1e-5f);
    float v = (a[idx] - mu) * inv * gamma[c] + beta[c];
    h[idx] += v;
}

// ---------------- head: out = softmax(h @ W_head + b_head) ----------------
__global__ __launch_bounds__(64) void k_head(const float* __restrict__ h,
                                             const float* __restrict__ W,
                                             const float* __restrict__ b,
                                             float* __restrict__ out) {
    __shared__ float hs[H];
    int n = blockIdx.x, t = threadIdx.x;
    hs[t] = h[n * H + t];
    hs[t + 64] = h[n * H + 64 + t];
    __syncthreads();
    float logit = -1e30f;
    if (t < ODIM) {
        float acc = b[t];
#pragma unroll 8
        for (int k = 0; k < H; k++) acc = fmaf(hs[k], W[k * ODIM + t], acc);
        logit = acc;
    }
    float m = logit;
    for (int off = 32; off; off >>= 1) m = fmaxf(m, __shfl_xor(m, off));
    float e = (t < ODIM) ? __expf(logit - m) : 0.0f;
    float s = e;
    for (int off = 32; off; off >>= 1) s += __shfl_xor(s, off);
    if (t < ODIM) out[n * ODIM + t] = e / s;
}

extern "C" void kernel_launch(void* const* d_in, const int* in_sizes, int n_in,
                              void* d_out, int out_size, void* d_ws, size_t ws_size,
                              hipStream_t stream) {
    const float* x = (const float*)d_in[0];
    const int* edge_index = (const int*)d_in[1];  // [2,E]
    const float* W_in = (const float*)d_in[2];
    const float* b_in = (const float*)d_in[3];
    const float* centers = (const float*)d_in[4];  // [L,R,H]
    const float* widths = (const float*)d_in[5];
    const float* Wc = (const float*)d_in[6];  // [L,R,H,H]
    const float* bc = (const float*)d_in[7];
    const float* bn_gamma = (const float*)d_in[8];
    const float* bn_beta = (const float*)d_in[9];
    const float* W_head = (const float*)d_in[10];
    const float* b_head = (const float*)d_in[11];
    float* out = (float*)d_out;

    const int* src = edge_index;
    const int* dst = edge_index + NE;

    // workspace layout
    float* h = (float*)d_ws;
    float* msg = h + NN * H;
    float* a = msg + NN * H;
    float* wmem = a + NN * H;       // [N,R]
    float* invdeg = wmem + NN * R;  // [N]
    float* sums = invdeg + NN;      // [256]
    int* counts = (int*)(sums + 2 * H);
    int* row_start = counts + NN;   // [N+1]
    int* cursor = row_start + NN + 1;
    int* esrc = cursor + NN;        // [E]

    // CSR build (once per call)
    hipMemsetAsync(counts, 0, NN * sizeof(int), stream);
    k_hist<<<NE / 256, 256, 0, stream>>>(dst, counts);
    k_scan<<<1, 1024, 0, stream>>>(counts, row_start, cursor, invdeg);
    k_fill<<<NE / 256, 256, 0, stream>>>(src, dst, cursor, esrc);

    // input layer
    k_in<<<NN, 128, 0, stream>>>(x, W_in, b_in, h);

    for (int l = 0; l < NL; l++) {
        k_memb<<<NN, 128, 0, stream>>>(h, centers + l * R * H, widths + l * R * H, wmem);
        k_gemm<<<NN / 64, 256, 0, stream>>>(h, wmem, Wc + l * R * H * H, bc + l * R * H, msg);
        k_agg<<<NN, 128, 0, stream>>>(msg, row_start, esrc, invdeg, a);
        hipMemsetAsync(sums, 0, 2 * H * sizeof(float), stream);
        k_bnstats<<<256, 128, 0, stream>>>(a, sums);
        k_bnapply<<<NN * H / 256, 256, 0, stream>>>(a, sums, bn_gamma + l * H,
                                                    bn_beta + l * H, h);
    }
    k_head<<<NN, 64, 0, stream>>>(h, W_head, b_head, out);
}

// Round 2
// 1058.225 us; speedup vs baseline: 1.6142x; 1.6142x over previous
//
#include <hip/hip_runtime.h>
#include <hip/hip_bf16.h>
#include <stdint.h>

// FLGNN round 2: rule-mix GEMM -> bf16 MFMA (16x16x32), h/w in registers,
// B staged via global_load_lds from pre-transposed+swizzled bf16 Wc.
// Everything else unchanged from round 1.

#define NN 32768
#define NE 1048576
#define H 128
#define R 16
#define NL 3
#define ODIM 40

typedef short bf16x8 __attribute__((ext_vector_type(8)));
typedef float f32x4 __attribute__((ext_vector_type(4)));

__device__ inline short f2bf_fast(float f) {  // round-half-up, 3 VALU
    unsigned u = __float_as_uint(f);
    return (short)((u + 0x8000u) >> 16);
}
__device__ inline short f2bf_rne(float f) {   // proper RNE (cold paths)
    unsigned u = __float_as_uint(f);
    u += 0x7FFFu + ((u >> 16) & 1u);
    return (short)(u >> 16);
}

__device__ inline void gload_lds16(const void* g, void* l) {
    __builtin_amdgcn_global_load_lds(
        (const __attribute__((address_space(1))) unsigned*)g,
        (__attribute__((address_space(3))) unsigned*)l, 16, 0, 0);
}

// ---------------- CSR build ----------------
__global__ void k_hist(const int* __restrict__ dst, int* __restrict__ counts) {
    int e = blockIdx.x * blockDim.x + threadIdx.x;
    if (e < NE) atomicAdd(&counts[dst[e]], 1);
}

__global__ __launch_bounds__(1024) void k_scan(const int* __restrict__ counts,
                                               int* __restrict__ row_start,
                                               int* __restrict__ cursor,
                                               float* __restrict__ invdeg) {
    __shared__ int ssum[1024];
    int t = threadIdx.x;
    int base = t * 32;
    int s = 0;
    for (int i = 0; i < 32; i++) s += counts[base + i];
    ssum[t] = s;
    __syncthreads();
    for (int off = 1; off < 1024; off <<= 1) {
        int v = (t >= off) ? ssum[t - off] : 0;
        __syncthreads();
        ssum[t] += v;
        __syncthreads();
    }
    int run = (t == 0) ? 0 : ssum[t - 1];
    for (int i = 0; i < 32; i++) {
        int c = counts[base + i];
        row_start[base + i] = run;
        cursor[base + i] = run;
        invdeg[base + i] = 1.0f / fmaxf((float)c, 1.0f);
        run += c;
    }
    if (t == 1023) row_start[NN] = run;
}

__global__ void k_fill(const int* __restrict__ src, const int* __restrict__ dst,
                       int* __restrict__ cursor, int* __restrict__ esrc) {
    int e = blockIdx.x * blockDim.x + threadIdx.x;
    if (e < NE) {
        int p = atomicAdd(&cursor[dst[e]], 1);
        esrc[p] = src[e];
    }
}

// ---------------- Wc -> bf16, transposed ([l,r][o][k]) + XOR-swizzled ------
// dst granule layout matches LDS b_frag reads: element (l_r, o, k) stored at
//   (l_r*16384) + o*128 + ((kb ^ (o&7))*8) + (k&7),  kb = k>>3.
__global__ __launch_bounds__(256) void k_cvtB(const float* __restrict__ Wc,
                                              short* __restrict__ WcT) {
    int s = blockIdx.x * 256 + threadIdx.x;  // src-linear: coalesced reads
    int lr = s >> 14;
    int rem = s & 16383;
    int k = rem >> 7;
    int o = rem & 127;
    int kb = k >> 3;
    int d = lr * 16384 + o * 128 + (((kb ^ (o & 7)) << 3)) + (k & 7);
    WcT[d] = f2bf_rne(Wc[s]);
}

// ---------------- input layer: h = relu(x @ W_in + b_in) ----------------
__global__ __launch_bounds__(128) void k_in(const float* __restrict__ x,
                                            const float* __restrict__ W,
                                            const float* __restrict__ b,
                                            float* __restrict__ h) {
    __shared__ float xs[H];
    int n = blockIdx.x, t = threadIdx.x;
    xs[t] = x[n * H + t];
    __syncthreads();
    float acc = b[t];
#pragma unroll 8
    for (int k = 0; k < H; k++) acc = fmaf(xs[k], W[k * H + t], acc);
    h[n * H + t] = fmaxf(acc, 0.0f);
}

// ---------------- memberships ----------------
__global__ __launch_bounds__(128) void k_memb(const float* __restrict__ h,
                                              const float* __restrict__ centers,
                                              const float* __restrict__ widths,
                                              float* __restrict__ wout) {
    __shared__ float hs[H];
    __shared__ float sm[R];
    int n = blockIdx.x, t = threadIdx.x;
    hs[t] = h[n * H + t];
    __syncthreads();
    int r = t >> 3, lane = t & 7;
    float s = 0.0f;
#pragma unroll
    for (int j = lane; j < H; j += 8) {
        float c = centers[r * H + j];
        float wd = widths[r * H + j];
        float d = hs[j] - c;
        s += d * d * (0.5f / (wd * wd));
    }
    s += __shfl_down(s, 4, 8);
    s += __shfl_down(s, 2, 8);
    s += __shfl_down(s, 1, 8);
    if (lane == 0) sm[r] = s * (1.0f / 128.0f);
    __syncthreads();
    if (t < R) {
        float v = -sm[t];
        float m = v;
        for (int off = 8; off; off >>= 1) m = fmaxf(m, __shfl_xor(m, off, R));
        float e = __expf(v - m);
        float sum = e;
        for (int off = 8; off; off >>= 1) sum += __shfl_xor(sum, off, R);
        wout[n * R + t] = e / sum;
    }
}

// ---------------- rule-mix GEMM via MFMA ----------------
// msg[64 rows x 128 cols per block] = sum_r (w_r * h) @ Wc_r + (w @ bc)
// 4 waves, wave wv = rows [row0+wv*16, +16). h,w in registers; B in LDS.
__global__ __launch_bounds__(256) void k_gemm_mfma(
    const float* __restrict__ h, const float* __restrict__ wgt,
    const short* __restrict__ BT,   // layer slice of WcT: [16][128][128] bf16
    const float* __restrict__ bc,   // layer slice: [16][128] f32
    float* __restrict__ msg) {
    __shared__ short Bs[16384];  // 32 KB: [o][k-granules, XOR-swizzled]
    int tid = threadIdx.x;
    int lane = tid & 63;
    int wv = tid >> 6;
    int quad = lane >> 4;
    int lm = lane & 15;
    int row0 = blockIdx.x * 64;
    int m = row0 + wv * 16 + lm;  // this lane's A row

    // preload h fragments: hreg[kc][j] = h[m][kc*32 + quad*8 + j]
    float hreg[4][8];
    const float* hrow = h + m * H + quad * 8;
#pragma unroll
    for (int kc = 0; kc < 4; kc++) {
        f32x4 a = *(const f32x4*)(hrow + kc * 32);
        f32x4 b = *(const f32x4*)(hrow + kc * 32 + 4);
        hreg[kc][0] = a.x; hreg[kc][1] = a.y; hreg[kc][2] = a.z; hreg[kc][3] = a.w;
        hreg[kc][4] = b.x; hreg[kc][5] = b.y; hreg[kc][6] = b.z; hreg[kc][7] = b.w;
    }
    // preload w[m][0..15]
    float wreg[16];
#pragma unroll
    for (int i = 0; i < 4; i++) {
        f32x4 v = *(const f32x4*)(wgt + m * R + i * 4);
        wreg[i * 4 + 0] = v.x; wreg[i * 4 + 1] = v.y;
        wreg[i * 4 + 2] = v.z; wreg[i * 4 + 3] = v.w;
    }

    f32x4 acc[8];
#pragma unroll
    for (int c = 0; c < 8; c++) acc[c] = (f32x4){0.f, 0.f, 0.f, 0.f};

    for (int r = 0; r < R; r++) {
        __syncthreads();  // Bs consumers from prev iter done
        // stage B_r (32 KB) via async global->LDS, 16B/lane
        const char* gsrc = (const char*)(BT + r * 16384) + wv * 8192 + lane * 16;
        char* ldst = (char*)Bs + wv * 8192;  // wave-uniform; HW adds lane*16
#pragma unroll
        for (int c = 0; c < 8; c++)
            gload_lds16(gsrc + c * 1024, ldst + c * 1024);
        __syncthreads();  // drains vmcnt -> Bs ready

        float wr = wreg[r];
#pragma unroll
        for (int kc = 0; kc < 4; kc++) {
            bf16x8 af;
#pragma unroll
            for (int j = 0; j < 8; j++) af[j] = f2bf_fast(wr * hreg[kc][j]);
#pragma unroll
            for (int c = 0; c < 8; c++) {
                int o = c * 16 + lm;
                const bf16x8* bp =
                    (const bf16x8*)&Bs[o * 128 + (((kc * 4 + quad) ^ (o & 7)) << 3)];
                acc[c] = __builtin_amdgcn_mfma_f32_16x16x32_bf16(af, *bp, acc[c], 0, 0, 0);
            }
        }
    }

    // ---- bias as one extra K=32 step: A=w (k<16, else 0), B=bc ----
    __syncthreads();
    for (int g = tid; g < 512; g += 256) {  // 512 granules of 8 bf16
        int o = g >> 2, kb = g & 3;
        bf16x8 v;
#pragma unroll
        for (int j = 0; j < 8; j++) {
            int k = kb * 8 + j;
            v[j] = (k < R) ? f2bf_rne(bc[k * H + o]) : (short)0;
        }
        *(bf16x8*)&Bs[o * 128 + (((kb ^ (o & 7)) << 3))] = v;
    }
    __syncthreads();
    bf16x8 abias;
#pragma unroll
    for (int j = 0; j < 8; j++)
        abias[j] = (quad < 2) ? f2bf_rne(wreg[quad * 8 + j]) : (short)0;
#pragma unroll
    for (int c = 0; c < 8; c++) {
        int o = c * 16 + lm;
        const bf16x8* bp = (const bf16x8*)&Bs[o * 128 + (((quad ^ (o & 7)) << 3))];
        acc[c] = __builtin_amdgcn_mfma_f32_16x16x32_bf16(abias, *bp, acc[c], 0, 0, 0);
    }

    // ---- store: C/D layout row=(quad*4+v), col=lm ----
    int orow = row0 + wv * 16 + quad * 4;
#pragma unroll
    for (int c = 0; c < 8; c++) {
        int col = c * 16 + lm;
#pragma unroll
        for (int v = 0; v < 4; v++) msg[(orow + v) * H + col] = acc[c][v];
    }
}

// ---------------- CSR aggregate ----------------
__global__ __launch_bounds__(128) void k_agg(const float* __restrict__ msg,
                                             const int* __restrict__ row_start,
                                             const int* __restrict__ esrc,
                                             const float* __restrict__ invdeg,
                                             float* __restrict__ a) {
    int n = blockIdx.x, t = threadIdx.x;
    int b = row_start[n], e = row_start[n + 1];
    float acc = 0.0f;
    for (int i = b; i < e; i++) {
        int s = esrc[i];
        acc += msg[s * H + t];
    }
    a[n * H + t] = fmaxf(acc * invdeg[n], 0.0f);
}

// ---------------- BatchNorm stats ----------------
__global__ __launch_bounds__(128) void k_bnstats(const float* __restrict__ a,
                                                 float* __restrict__ sums) {
    int t = threadIdx.x;
    float s = 0.0f, s2 = 0.0f;
    for (int n = blockIdx.x; n < NN; n += gridDim.x) {
        float v = a[n * H + t];
        s += v;
        s2 += v * v;
    }
    atomicAdd(&sums[t], s);
    atomicAdd(&sums[H + t], s2);
}

// ---------------- BN apply + residual ----------------
__global__ __launch_bounds__(256) void k_bnapply(const float* __restrict__ a,
                                                 const float* __restrict__ sums,
                                                 const float* __restrict__ gamma,
                                                 const float* __restrict__ beta,
                                                 float* __restrict__ h) {
    int idx = blockIdx.x * 256 + threadIdx.x;
    int c = idx & (H - 1);
    float mu = sums[c] * (1.0f / NN);
    float var = sums[H + c] * (1.0f / NN) - mu * mu;
    float inv = rsqrtf(var + 1e-5f);
    float v = (a[idx] - mu) * inv * gamma[c] + beta[c];
    h[idx] += v;
}

// ---------------- head softmax ----------------
__global__ __launch_bounds__(64) void k_head(const float* __restrict__ h,
                                             const float* __restrict__ W,
                                             const float* __restrict__ b,
                                             float* __restrict__ out) {
    __shared__ float hs[H];
    int n = blockIdx.x, t = threadIdx.x;
    hs[t] = h[n * H + t];
    hs[t + 64] = h[n * H + 64 + t];
    __syncthreads();
    float logit = -1e30f;
    if (t < ODIM) {
        float acc = b[t];
#pragma unroll 8
        for (int k = 0; k < H; k++) acc = fmaf(hs[k], W[k * ODIM + t], acc);
        logit = acc;
    }
    float m = logit;
    for (int off = 32; off; off >>= 1) m = fmaxf(m, __shfl_xor(m, off));
    float e = (t < ODIM) ? __expf(logit - m) : 0.0f;
    float s = e;
    for (int off = 32; off; off >>= 1) s += __shfl_xor(s, off);
    if (t < ODIM) out[n * ODIM + t] = e / s;
}

extern "C" void kernel_launch(void* const* d_in, const int* in_sizes, int n_in,
                              void* d_out, int out_size, void* d_ws, size_t ws_size,
                              hipStream_t stream) {
    const float* x = (const float*)d_in[0];
    const int* edge_index = (const int*)d_in[1];
    const float* W_in = (const float*)d_in[2];
    const float* b_in = (const float*)d_in[3];
    const float* centers = (const float*)d_in[4];
    const float* widths = (const float*)d_in[5];
    const float* Wc = (const float*)d_in[6];
    const float* bc = (const float*)d_in[7];
    const float* bn_gamma = (const float*)d_in[8];
    const float* bn_beta = (const float*)d_in[9];
    const float* W_head = (const float*)d_in[10];
    const float* b_head = (const float*)d_in[11];
    float* out = (float*)d_out;

    const int* src = edge_index;
    const int* dst = edge_index + NE;

    // workspace layout
    float* h = (float*)d_ws;
    float* msg = h + NN * H;
    float* a = msg + NN * H;
    float* wmem = a + NN * H;       // [N,R]
    float* invdeg = wmem + NN * R;  // [N]
    float* sums = invdeg + NN;      // [256]
    int* counts = (int*)(sums + 2 * H);
    int* row_start = counts + NN;   // [N+1]
    int* cursor = counts;           // alias: k_scan reads counts before writing cursor
    int* esrc = row_start + NN + 1; // [E]
    uintptr_t p = (uintptr_t)(esrc + NE);
    short* WcT = (short*)((p + 63) & ~(uintptr_t)63);  // [3][16][128][128] bf16

    // Wc -> bf16 transposed+swizzled (once per call)
    k_cvtB<<<NL * R * H * H / 256, 256, 0, stream>>>(Wc, WcT);

    // CSR build
    hipMemsetAsync(counts, 0, NN * sizeof(int), stream);
    k_hist<<<NE / 256, 256, 0, stream>>>(dst, counts);
    k_scan<<<1, 1024, 0, stream>>>(counts, row_start, cursor, invdeg);
    k_fill<<<NE / 256, 256, 0, stream>>>(src, dst, cursor, esrc);

    // input layer
    k_in<<<NN, 128, 0, stream>>>(x, W_in, b_in, h);

    for (int l = 0; l < NL; l++) {
        k_memb<<<NN, 128, 0, stream>>>(h, centers + l * R * H, widths + l * R * H, wmem);
        k_gemm_mfma<<<NN / 64, 256, 0, stream>>>(h, wmem, WcT + l * R * H * H,
                                                 bc + l * R * H, msg);
        k_agg<<<NN, 128, 0, stream>>>(msg, row_start, esrc, invdeg, a);
        hipMemsetAsync(sums, 0, 2 * H * sizeof(float), stream);
        k_bnstats<<<256, 128, 0, stream>>>(a, sums);
        k_bnapply<<<NN * H / 256, 256, 0, stream>>>(a, sums, bn_gamma + l * H,
                                                    bn_beta + l * H, h);
    }
    k_head<<<NN, 64, 0, stream>>>(h, W_head, b_head, out);
}

// Round 3
// 628.275 us; speedup vs baseline: 2.7189x; 1.6843x over previous
//
#include <hip/hip_runtime.h>
#include <hip/hip_bf16.h>
#include <stdint.h>

// FLGNN round 3: bf16 msg gather (halve agg bytes), split-A (hi/lo) MFMA GEMM
// with fp32 per-rule scaling (more accurate than round 2), memberships fused
// into GEMM prologue, MFMA input layer + head, vectorized BN apply.

#define NN 32768
#define NE 1048576
#define H 128
#define R 16
#define NL 3
#define ODIM 40

typedef short bf16x8 __attribute__((ext_vector_type(8)));
typedef float f32x4 __attribute__((ext_vector_type(4)));
typedef unsigned short u16x4 __attribute__((ext_vector_type(4)));

__device__ inline short f2bf_rne(float f) {
    unsigned u = __float_as_uint(f);
    u += 0x7FFFu + ((u >> 16) & 1u);
    return (short)(u >> 16);
}
__device__ inline void split_bf(float v, short& hi, short& lo) {
    unsigned u = __float_as_uint(v);
    unsigned uh = (u + 0x7FFFu + ((u >> 16) & 1u)) & 0xFFFF0000u;
    hi = (short)(uh >> 16);
    lo = f2bf_rne(v - __uint_as_float(uh));
}
__device__ inline f32x4 bf4f(u16x4 v) {
    f32x4 r;
    r.x = __uint_as_float((unsigned)v.x << 16);
    r.y = __uint_as_float((unsigned)v.y << 16);
    r.z = __uint_as_float((unsigned)v.z << 16);
    r.w = __uint_as_float((unsigned)v.w << 16);
    return r;
}
__device__ inline void gload_lds16(const void* g, void* l) {
    __builtin_amdgcn_global_load_lds(
        (const __attribute__((address_space(1))) unsigned*)g,
        (__attribute__((address_space(3))) unsigned*)l, 16, 0, 0);
}

// ---------------- CSR build ----------------
__global__ void k_hist(const int* __restrict__ dst, int* __restrict__ counts) {
    int e = blockIdx.x * blockDim.x + threadIdx.x;
    if (e < NE) atomicAdd(&counts[dst[e]], 1);
}

__global__ __launch_bounds__(1024) void k_scan(const int* __restrict__ counts,
                                               int* __restrict__ row_start,
                                               int* __restrict__ cursor,
                                               float* __restrict__ invdeg) {
    __shared__ int ssum[1024];
    int t = threadIdx.x;
    int base = t * 32;
    int s = 0;
    for (int i = 0; i < 32; i++) s += counts[base + i];
    ssum[t] = s;
    __syncthreads();
    for (int off = 1; off < 1024; off <<= 1) {
        int v = (t >= off) ? ssum[t - off] : 0;
        __syncthreads();
        ssum[t] += v;
        __syncthreads();
    }
    int run = (t == 0) ? 0 : ssum[t - 1];
    for (int i = 0; i < 32; i++) {
        int c = counts[base + i];
        row_start[base + i] = run;
        cursor[base + i] = run;
        invdeg[base + i] = 1.0f / fmaxf((float)c, 1.0f);
        run += c;
    }
    if (t == 1023) row_start[NN] = run;
}

__global__ void k_fill(const int* __restrict__ src, const int* __restrict__ dst,
                       int* __restrict__ cursor, int* __restrict__ esrc) {
    int e = blockIdx.x * blockDim.x + threadIdx.x;
    if (e < NE) {
        int p = atomicAdd(&cursor[dst[e]], 1);
        esrc[p] = src[e];
    }
}

// ---------------- weight preprocessing ----------------
// Wc[l,r][k][o] f32 -> WcT bf16 at (l,r)*16384 + o*128 + ((kb^(o&7))<<3)+(k&7)
__global__ __launch_bounds__(256) void k_cvtB(const float* __restrict__ Wc,
                                              short* __restrict__ WcT) {
    int s = blockIdx.x * 256 + threadIdx.x;
    int lr = s >> 14;
    int rem = s & 16383;
    int k = rem >> 7;
    int o = rem & 127;
    int kb = k >> 3;
    int d = lr * 16384 + o * 128 + (((kb ^ (o & 7)) << 3)) + (k & 7);
    WcT[d] = f2bf_rne(Wc[s]);
}

// W_in[k][o] (128x128) -> hi/lo swizzled [o][k]
__global__ __launch_bounds__(256) void k_cvtW(const float* __restrict__ W,
                                              short* __restrict__ Whi,
                                              short* __restrict__ Wlo) {
    int t = blockIdx.x * 256 + threadIdx.x;  // 16384
    int k = t >> 7, o = t & 127;
    int kb = k >> 3;
    int d = o * 128 + (((kb ^ (o & 7)) << 3)) + (k & 7);
    short hi, lo;
    split_bf(W[k * 128 + o], hi, lo);
    Whi[d] = hi;
    Wlo[d] = lo;
}

// W_head[k][o<40] -> padded 48 cols, hi/lo swizzled [o][k]
__global__ __launch_bounds__(256) void k_cvtH(const float* __restrict__ W,
                                              short* __restrict__ Whi,
                                              short* __restrict__ Wlo) {
    int t = blockIdx.x * 256 + threadIdx.x;  // 48*128 = 6144
    int o = t >> 7, k = t & 127;
    float v = (o < ODIM) ? W[k * ODIM + o] : 0.0f;
    int kb = k >> 3;
    int d = o * 128 + (((kb ^ (o & 7)) << 3)) + (k & 7);
    short hi, lo;
    split_bf(v, hi, lo);
    Whi[d] = hi;
    Wlo[d] = lo;
}

// IW[l,r,j] = 0.5/(width^2)/128
__global__ __launch_bounds__(256) void k_prep(const float* __restrict__ widths,
                                              float* __restrict__ IW) {
    int t = blockIdx.x * 256 + threadIdx.x;  // NL*R*H = 6144
    float wd = widths[t];
    IW[t] = 0.5f / (wd * wd) * (1.0f / 128.0f);
}

// ---------------- input layer via MFMA: h = relu(x @ W_in + b_in) ----------
__global__ __launch_bounds__(256, 2) void k_in_mfma(
    const float* __restrict__ x, const short* __restrict__ Whi,
    const short* __restrict__ Wlo, const float* __restrict__ b,
    float* __restrict__ h) {
    __shared__ short Bs[16384];
    int tid = threadIdx.x, lane = tid & 63, wv = tid >> 6;
    int quad = lane >> 4, lm = lane & 15;
    int row0 = blockIdx.x * 64;
    int m = row0 + wv * 16 + lm;

    bf16x8 ahi[4], alo[4];
#pragma unroll
    for (int kc = 0; kc < 4; kc++) {
        f32x4 va = *(const f32x4*)(x + m * H + kc * 32 + quad * 8);
        f32x4 vb = *(const f32x4*)(x + m * H + kc * 32 + quad * 8 + 4);
        float vv[8] = {va.x, va.y, va.z, va.w, vb.x, vb.y, vb.z, vb.w};
#pragma unroll
        for (int j = 0; j < 8; j++) {
            short hi, lo;
            split_bf(vv[j], hi, lo);
            ahi[kc][j] = hi;
            alo[kc][j] = lo;
        }
    }
    f32x4 acc[8];
#pragma unroll
    for (int c = 0; c < 8; c++) acc[c] = (f32x4){0.f, 0.f, 0.f, 0.f};

    char* ldst = (char*)Bs + wv * 8192;
    const char* g1 = (const char*)Whi + wv * 8192 + lane * 16;
#pragma unroll
    for (int cc = 0; cc < 8; cc++) gload_lds16(g1 + cc * 1024, ldst + cc * 1024);
    __syncthreads();
#pragma unroll
    for (int kc = 0; kc < 4; kc++)
#pragma unroll
        for (int c = 0; c < 8; c++) {
            int o = c * 16 + lm;
            bf16x8 bfr = *(const bf16x8*)&Bs[o * 128 + (((kc * 4 + quad) ^ (o & 7)) << 3)];
            acc[c] = __builtin_amdgcn_mfma_f32_16x16x32_bf16(ahi[kc], bfr, acc[c], 0, 0, 0);
            acc[c] = __builtin_amdgcn_mfma_f32_16x16x32_bf16(alo[kc], bfr, acc[c], 0, 0, 0);
        }
    __syncthreads();
    const char* g2 = (const char*)Wlo + wv * 8192 + lane * 16;
#pragma unroll
    for (int cc = 0; cc < 8; cc++) gload_lds16(g2 + cc * 1024, ldst + cc * 1024);
    __syncthreads();
#pragma unroll
    for (int kc = 0; kc < 4; kc++)
#pragma unroll
        for (int c = 0; c < 8; c++) {
            int o = c * 16 + lm;
            bf16x8 bfr = *(const bf16x8*)&Bs[o * 128 + (((kc * 4 + quad) ^ (o & 7)) << 3)];
            acc[c] = __builtin_amdgcn_mfma_f32_16x16x32_bf16(ahi[kc], bfr, acc[c], 0, 0, 0);
        }
    int orow = row0 + wv * 16 + quad * 4;
#pragma unroll
    for (int c = 0; c < 8; c++) {
        int col = c * 16 + lm;
        float bi = b[col];
#pragma unroll
        for (int v = 0; v < 4; v++)
            h[(orow + v) * H + col] = fmaxf(acc[c][v] + bi, 0.0f);
    }
}

// ---------------- fused memberships + rule-mix GEMM ----------------
// Per 64-row block: compute w (softmax over rules) in prologue, then
// msg = sum_r w_r * (h @ Wc_r) + (w @ bc) with split-A MFMA, bf16 output.
__global__ __launch_bounds__(256, 2) void k_gemm_mfma(
    const float* __restrict__ h, const short* __restrict__ BT,
    const float* __restrict__ bc, const float* __restrict__ cen,
    const float* __restrict__ iw, unsigned short* __restrict__ msgb) {
    __shared__ __align__(16) char smemu[33792];  // union: Bs (32KB) / hs[64][132]
    short* Bs = (short*)smemu;
    float(*hs)[132] = (float(*)[132])smemu;
    __shared__ float wsh[16][64];  // wsh[r][row] = firing strength
    __shared__ float sm[64][17];   // raw scores (padded)

    int tid = threadIdx.x, lane = tid & 63, wv = tid >> 6;
    int quad = lane >> 4, lm = lane & 15;
    int row0 = blockIdx.x * 64;

    // stage h tile (64x128 f32), coalesced
    {
        const f32x4* hg = (const f32x4*)(h + row0 * H);
        for (int g = tid; g < 2048; g += 256) {
            int rr = g >> 5, cc = (g & 31) << 2;
            *(f32x4*)&hs[rr][cc] = hg[g];
        }
    }
    __syncthreads();

    // membership partial scores: wave wv -> rules wv*4..+3, lane = row
    {
        int wvu = __builtin_amdgcn_readfirstlane(wv);
        const float* c0 = cen + (wvu * 4 + 0) * H;
        const float* c1 = cen + (wvu * 4 + 1) * H;
        const float* c2 = cen + (wvu * 4 + 2) * H;
        const float* c3 = cen + (wvu * 4 + 3) * H;
        const float* w0 = iw + (wvu * 4 + 0) * H;
        const float* w1 = iw + (wvu * 4 + 1) * H;
        const float* w2 = iw + (wvu * 4 + 2) * H;
        const float* w3 = iw + (wvu * 4 + 3) * H;
        float s0 = 0.f, s1 = 0.f, s2 = 0.f, s3 = 0.f;
#pragma unroll 4
        for (int j0 = 0; j0 < H; j0 += 4) {
            f32x4 hv = *(const f32x4*)&hs[lane][j0];
            f32x4 cv, wv4, d;
            cv = *(const f32x4*)(c0 + j0); wv4 = *(const f32x4*)(w0 + j0);
            d = hv - cv;
            s0 += d.x * d.x * wv4.x + d.y * d.y * wv4.y + d.z * d.z * wv4.z + d.w * d.w * wv4.w;
            cv = *(const f32x4*)(c1 + j0); wv4 = *(const f32x4*)(w1 + j0);
            d = hv - cv;
            s1 += d.x * d.x * wv4.x + d.y * d.y * wv4.y + d.z * d.z * wv4.z + d.w * d.w * wv4.w;
            cv = *(const f32x4*)(c2 + j0); wv4 = *(const f32x4*)(w2 + j0);
            d = hv - cv;
            s2 += d.x * d.x * wv4.x + d.y * d.y * wv4.y + d.z * d.z * wv4.z + d.w * d.w * wv4.w;
            cv = *(const f32x4*)(c3 + j0); wv4 = *(const f32x4*)(w3 + j0);
            d = hv - cv;
            s3 += d.x * d.x * wv4.x + d.y * d.y * wv4.y + d.z * d.z * wv4.z + d.w * d.w * wv4.w;
        }
        sm[lane][wvu * 4 + 0] = s0;
        sm[lane][wvu * 4 + 1] = s1;
        sm[lane][wvu * 4 + 2] = s2;
        sm[lane][wvu * 4 + 3] = s3;
    }

    // extract this lane's A-row fragments (hi/lo split), from LDS
    bf16x8 ahi[4], alo[4];
    {
        int m = wv * 16 + lm;
#pragma unroll
        for (int kc = 0; kc < 4; kc++) {
            f32x4 va = *(const f32x4*)&hs[m][kc * 32 + quad * 8];
            f32x4 vb = *(const f32x4*)&hs[m][kc * 32 + quad * 8 + 4];
            float vv[8] = {va.x, va.y, va.z, va.w, vb.x, vb.y, vb.z, vb.w};
#pragma unroll
            for (int j = 0; j < 8; j++) {
                short hi, lo;
                split_bf(vv[j], hi, lo);
                ahi[kc][j] = hi;
                alo[kc][j] = lo;
            }
        }
    }
    __syncthreads();

    // softmax over 16 rules per row -> wsh[r][row]
    if (tid < 64) {
        float v[16], mx = -1e30f;
#pragma unroll
        for (int r = 0; r < R; r++) {
            v[r] = -sm[tid][r];
            mx = fmaxf(mx, v[r]);
        }
        float sum = 0.f, e[16];
#pragma unroll
        for (int r = 0; r < R; r++) {
            e[r] = __expf(v[r] - mx);
            sum += e[r];
        }
        float inv = 1.0f / sum;
#pragma unroll
        for (int r = 0; r < R; r++) wsh[r][tid] = e[r] * inv;
    }

    f32x4 out[8];
#pragma unroll
    for (int c = 0; c < 8; c++) out[c] = (f32x4){0.f, 0.f, 0.f, 0.f};

    char* ldst = (char*)Bs + wv * 8192;
    for (int r = 0; r < R; r++) {
        __syncthreads();  // prev consumers done (also covers wsh/hs ordering)
        const char* gsrc = (const char*)(BT + r * 16384) + wv * 8192 + lane * 16;
#pragma unroll
        for (int cc = 0; cc < 8; cc++) gload_lds16(gsrc + cc * 1024, ldst + cc * 1024);
        __syncthreads();

        f32x4 accr[8];
#pragma unroll
        for (int c = 0; c < 8; c++) accr[c] = (f32x4){0.f, 0.f, 0.f, 0.f};
#pragma unroll
        for (int kc = 0; kc < 4; kc++)
#pragma unroll
            for (int c = 0; c < 8; c++) {
                int o = c * 16 + lm;
                bf16x8 bfr = *(const bf16x8*)&Bs[o * 128 + (((kc * 4 + quad) ^ (o & 7)) << 3)];
                accr[c] = __builtin_amdgcn_mfma_f32_16x16x32_bf16(ahi[kc], bfr, accr[c], 0, 0, 0);
                accr[c] = __builtin_amdgcn_mfma_f32_16x16x32_bf16(alo[kc], bfr, accr[c], 0, 0, 0);
            }
        // fp32 per-rule scale-accumulate; C-row v = quad*4+v
        f32x4 wr4 = *(const f32x4*)&wsh[r][wv * 16 + quad * 4];
#pragma unroll
        for (int c = 0; c < 8; c++) {
            out[c].x += wr4.x * accr[c].x;
            out[c].y += wr4.y * accr[c].y;
            out[c].z += wr4.z * accr[c].z;
            out[c].w += wr4.w * accr[c].w;
        }
    }

    // bias via one K=32 MFMA: A = w (k<16 else 0), B = bc
    __syncthreads();
    for (int g = tid; g < 512; g += 256) {
        int o = g >> 2, kb = g & 3;
        bf16x8 v;
#pragma unroll
        for (int j = 0; j < 8; j++) {
            int k = kb * 8 + j;
            v[j] = (k < R) ? f2bf_rne(bc[k * H + o]) : (short)0;
        }
        *(bf16x8*)&Bs[o * 128 + ((kb ^ (o & 7)) << 3)] = v;
    }
    bf16x8 abias;
#pragma unroll
    for (int j = 0; j < 8; j++)
        abias[j] = (quad < 2) ? f2bf_rne(wsh[quad * 8 + j][wv * 16 + lm]) : (short)0;
    __syncthreads();
#pragma unroll
    for (int c = 0; c < 8; c++) {
        int o = c * 16 + lm;
        bf16x8 bfr = *(const bf16x8*)&Bs[o * 128 + ((quad ^ (o & 7)) << 3)];
        out[c] = __builtin_amdgcn_mfma_f32_16x16x32_bf16(abias, bfr, out[c], 0, 0, 0);
    }

    // store msg as bf16
    int orow = row0 + wv * 16 + quad * 4;
#pragma unroll
    for (int c = 0; c < 8; c++) {
        int col = c * 16 + lm;
#pragma unroll
        for (int v = 0; v < 4; v++)
            msgb[(orow + v) * H + col] = (unsigned short)f2bf_rne(out[c][v]);
    }
}

// ---------------- CSR aggregate (bf16 gather) ----------------
__global__ __launch_bounds__(256) void k_agg(
    const unsigned short* __restrict__ msgb, const int* __restrict__ row_start,
    const int* __restrict__ esrc, const float* __restrict__ invdeg,
    float* __restrict__ a) {
    int tid = threadIdx.x;
    int g = tid >> 5, lane = tid & 31;
    int n = blockIdx.x * 8 + g;
    int b = row_start[n], e = row_start[n + 1];
    f32x4 a0 = {0.f, 0.f, 0.f, 0.f}, a1 = a0, a2 = a0, a3 = a0;
    int i = b;
    for (; i + 4 <= e; i += 4) {
        int s0 = esrc[i], s1 = esrc[i + 1], s2 = esrc[i + 2], s3 = esrc[i + 3];
        u16x4 v0 = *(const u16x4*)&msgb[s0 * H + lane * 4];
        u16x4 v1 = *(const u16x4*)&msgb[s1 * H + lane * 4];
        u16x4 v2 = *(const u16x4*)&msgb[s2 * H + lane * 4];
        u16x4 v3 = *(const u16x4*)&msgb[s3 * H + lane * 4];
        a0 += bf4f(v0);
        a1 += bf4f(v1);
        a2 += bf4f(v2);
        a3 += bf4f(v3);
    }
    for (; i < e; i++) {
        int s = esrc[i];
        a0 += bf4f(*(const u16x4*)&msgb[s * H + lane * 4]);
    }
    f32x4 t = (a0 + a1) + (a2 + a3);
    float id = invdeg[n];
    f32x4 res;
    res.x = fmaxf(t.x * id, 0.f);
    res.y = fmaxf(t.y * id, 0.f);
    res.z = fmaxf(t.z * id, 0.f);
    res.w = fmaxf(t.w * id, 0.f);
    *(f32x4*)&a[n * H + lane * 4] = res;
}

// ---------------- BatchNorm stats ----------------
__global__ __launch_bounds__(128) void k_bnstats(const float* __restrict__ a,
                                                 float* __restrict__ sums) {
    int t = threadIdx.x;
    float s = 0.0f, s2 = 0.0f;
    for (int n = blockIdx.x; n < NN; n += gridDim.x) {
        float v = a[n * H + t];
        s += v;
        s2 += v * v;
    }
    atomicAdd(&sums[t], s);
    atomicAdd(&sums[H + t], s2);
}

// ---------------- BN apply + residual (vectorized) ----------------
__global__ __launch_bounds__(256) void k_bnapply(
    const float* __restrict__ a, const float* __restrict__ sums,
    const float* __restrict__ gamma, const float* __restrict__ beta,
    float* __restrict__ h) {
    int t = blockIdx.x * 256 + threadIdx.x;
    int base = t * 4;
    int c4 = base & (H - 1);
    f32x4 s1 = *(const f32x4*)&sums[c4];
    f32x4 s2 = *(const f32x4*)&sums[H + c4];
    f32x4 gm = *(const f32x4*)&gamma[c4];
    f32x4 bt = *(const f32x4*)&beta[c4];
    f32x4 av = *(const f32x4*)&a[base];
    f32x4 hv = *(const f32x4*)&h[base];
    f32x4 res;
#define BN1(X)                                                        \
    {                                                                 \
        float mu = s1.X * (1.0f / NN);                                \
        float var = s2.X * (1.0f / NN) - mu * mu;                     \
        float inv = rsqrtf(var + 1e-5f);                              \
        res.X = hv.X + (av.X - mu) * inv * gm.X + bt.X;               \
    }
    BN1(x) BN1(y) BN1(z) BN1(w)
#undef BN1
    *(f32x4*)&h[base] = res;
}

// ---------------- head via MFMA + lane softmax ----------------
__global__ __launch_bounds__(256, 2) void k_head_mfma(
    const float* __restrict__ h, const short* __restrict__ Whi,
    const short* __restrict__ Wlo, const float* __restrict__ bh,
    float* __restrict__ out) {
    __shared__ short Bs[12288];  // [48 cols][128 k] hi then lo (6144 each)
    int tid = threadIdx.x, lane = tid & 63, wv = tid >> 6;
    int quad = lane >> 4, lm = lane & 15;
    int row0 = blockIdx.x * 64;
    int m = row0 + wv * 16 + lm;

    bf16x8 ahi[4], alo[4];
#pragma unroll
    for (int kc = 0; kc < 4; kc++) {
        f32x4 va = *(const f32x4*)(h + m * H + kc * 32 + quad * 8);
        f32x4 vb = *(const f32x4*)(h + m * H + kc * 32 + quad * 8 + 4);
        float vv[8] = {va.x, va.y, va.z, va.w, vb.x, vb.y, vb.z, vb.w};
#pragma unroll
        for (int j = 0; j < 8; j++) {
            short hi, lo;
            split_bf(vv[j], hi, lo);
            ahi[kc][j] = hi;
            alo[kc][j] = lo;
        }
    }
    {
        char* ldst = (char*)Bs + wv * 3072;
        const char* g1 = (const char*)Whi + wv * 3072 + lane * 16;
        const char* g2 = (const char*)Wlo + wv * 3072 + lane * 16;
#pragma unroll
        for (int cc = 0; cc < 3; cc++) gload_lds16(g1 + cc * 1024, ldst + cc * 1024);
        char* ldst2 = (char*)Bs + 12288 + wv * 3072;
#pragma unroll
        for (int cc = 0; cc < 3; cc++) gload_lds16(g2 + cc * 1024, ldst2 + cc * 1024);
    }
    __syncthreads();
    f32x4 acc[3];
#pragma unroll
    for (int c = 0; c < 3; c++) acc[c] = (f32x4){0.f, 0.f, 0.f, 0.f};
#pragma unroll
    for (int kc = 0; kc < 4; kc++)
#pragma unroll
        for (int c = 0; c < 3; c++) {
            int o = c * 16 + lm;
            int off = o * 128 + (((kc * 4 + quad) ^ (o & 7)) << 3);
            bf16x8 bH = *(const bf16x8*)&Bs[off];
            bf16x8 bL = *(const bf16x8*)&Bs[6144 + off];
            acc[c] = __builtin_amdgcn_mfma_f32_16x16x32_bf16(ahi[kc], bH, acc[c], 0, 0, 0);
            acc[c] = __builtin_amdgcn_mfma_f32_16x16x32_bf16(alo[kc], bH, acc[c], 0, 0, 0);
            acc[c] = __builtin_amdgcn_mfma_f32_16x16x32_bf16(ahi[kc], bL, acc[c], 0, 0, 0);
        }
    float bh0 = bh[lm], bh1 = bh[16 + lm];
    float bh2 = (lm < 8) ? bh[32 + lm] : 0.f;
    int orow = row0 + wv * 16 + quad * 4;
#pragma unroll
    for (int v = 0; v < 4; v++) {
        float v0 = acc[0][v] + bh0;
        float v1 = acc[1][v] + bh1;
        float v2 = (lm < 8) ? (acc[2][v] + bh2) : -1e30f;
        float mx = fmaxf(fmaxf(v0, v1), v2);
        for (int off = 8; off; off >>= 1) mx = fmaxf(mx, __shfl_xor(mx, off, 16));
        float e0 = __expf(v0 - mx), e1 = __expf(v1 - mx);
        float e2 = (lm < 8) ? __expf(v2 - mx) : 0.f;
        float s = e0 + e1 + e2;
        for (int off = 8; off; off >>= 1) s += __shfl_xor(s, off, 16);
        float inv = 1.0f / s;
        out[(orow + v) * ODIM + lm] = e0 * inv;
        out[(orow + v) * ODIM + 16 + lm] = e1 * inv;
        if (lm < 8) out[(orow + v) * ODIM + 32 + lm] = e2 * inv;
    }
}

extern "C" void kernel_launch(void* const* d_in, const int* in_sizes, int n_in,
                              void* d_out, int out_size, void* d_ws, size_t ws_size,
                              hipStream_t stream) {
    const float* x = (const float*)d_in[0];
    const int* edge_index = (const int*)d_in[1];
    const float* W_in = (const float*)d_in[2];
    const float* b_in = (const float*)d_in[3];
    const float* centers = (const float*)d_in[4];
    const float* widths = (const float*)d_in[5];
    const float* Wc = (const float*)d_in[6];
    const float* bc = (const float*)d_in[7];
    const float* bn_gamma = (const float*)d_in[8];
    const float* bn_beta = (const float*)d_in[9];
    const float* W_head = (const float*)d_in[10];
    const float* b_head = (const float*)d_in[11];
    float* out = (float*)d_out;

    const int* src = edge_index;
    const int* dst = edge_index + NE;

    // workspace layout
    float* h = (float*)d_ws;
    float* a = h + NN * H;
    float* invdeg = a + NN * H;
    float* sums = invdeg + NN;       // 256
    float* IW = sums + 2 * H;        // NL*R*H = 6144
    int* counts = (int*)(IW + NL * R * H);
    int* row_start = counts + NN;    // NN+1
    int* esrc = row_start + NN + 1;  // NE
    uintptr_t p = (uintptr_t)(esrc + NE);
    p = (p + 63) & ~(uintptr_t)63;
    unsigned short* msgb = (unsigned short*)p;   // NN*H bf16
    short* WcT = (short*)(msgb + NN * H);        // NL*R*H*H
    short* WinHi = WcT + NL * R * H * H;         // 16384
    short* WinLo = WinHi + 16384;
    short* WhHi = WinLo + 16384;                 // 6144
    short* WhLo = WhHi + 6144;

    // preprocessing (every call; ws is re-poisoned)
    k_cvtB<<<NL * R * H * H / 256, 256, 0, stream>>>(Wc, WcT);
    k_cvtW<<<64, 256, 0, stream>>>(W_in, WinHi, WinLo);
    k_cvtH<<<24, 256, 0, stream>>>(W_head, WhHi, WhLo);
    k_prep<<<24, 256, 0, stream>>>(widths, IW);

    // CSR build
    hipMemsetAsync(counts, 0, NN * sizeof(int), stream);
    k_hist<<<NE / 256, 256, 0, stream>>>(dst, counts);
    k_scan<<<1, 1024, 0, stream>>>(counts, row_start, counts, invdeg);
    k_fill<<<NE / 256, 256, 0, stream>>>(src, dst, counts, esrc);

    // input layer
    k_in_mfma<<<NN / 64, 256, 0, stream>>>(x, WinHi, WinLo, b_in, h);

    for (int l = 0; l < NL; l++) {
        k_gemm_mfma<<<NN / 64, 256, 0, stream>>>(h, WcT + l * R * H * H,
                                                 bc + l * R * H, centers + l * R * H,
                                                 IW + l * R * H, msgb);
        k_agg<<<NN / 8, 256, 0, stream>>>(msgb, row_start, esrc, invdeg, a);
        hipMemsetAsync(sums, 0, 2 * H * sizeof(float), stream);
        k_bnstats<<<512, 128, 0, stream>>>(a, sums);
        k_bnapply<<<NN * H / 1024, 256, 0, stream>>>(a, sums, bn_gamma + l * H,
                                                     bn_beta + l * H, h);
    }
    k_head_mfma<<<NN / 64, 256, 0, stream>>>(h, WhHi, WhLo, b_head, out);
}